// Round 8
// baseline (169.553 us; speedup 1.0000x reference)
//
#include <hip/hip_runtime.h>
#include <hip/hip_bf16.h>
#include <stdint.h>

#define N 8192
#define E 256
#define NUM_CLASSES 100
#define MARGIN 0.1f
#define EPS 1e-4f

#define BT 128                 // Gram tile dim
#define MT (N / BT)            // 64 tile-rows -> 2080 upper-tri tiles
#define NTILES (MT * (MT + 1) / 2)
#define EB 256                 // fp8 row = 256 B (full K resident in LDS)
#define NBLK 512               // exactly 2 blocks/CU x 256 CU -> all co-resident
#define FINB 32

typedef __attribute__((ext_vector_type(4))) float floatx4;
typedef const __attribute__((address_space(1))) void* gptr_t;
typedef __attribute__((address_space(3))) void* sptr_t;

struct Ctrl { double Ssum; int c0, c1, c2; };  // memset to 0 before launch

// 16-lane butterfly sum on the VALU via DPP (no LDS-pipe usage).
__device__ __forceinline__ float dpp_sum16(float v) {
  v += __int_as_float(__builtin_amdgcn_update_dpp(0, __float_as_int(v), 0xB1, 0xF, 0xF, true));
  v += __int_as_float(__builtin_amdgcn_update_dpp(0, __float_as_int(v), 0x4E, 0xF, 0xF, true));
  v += __int_as_float(__builtin_amdgcn_update_dpp(0, __float_as_int(v), 0x141, 0xF, 0xF, true));
  v += __int_as_float(__builtin_amdgcn_update_dpp(0, __float_as_int(v), 0x140, 0xF, 0xF, true));
  return v;
}

// linear upper-triangle tile id -> (by, bx), bx >= by
__device__ __forceinline__ void decode_tile(int t, int& by, int& bx) {
  int y = (int)((2.0 * MT + 1.0 -
                 __builtin_sqrt((2.0 * MT + 1.0) * (2.0 * MT + 1.0) - 8.0 * t)) * 0.5);
  while (y * MT - y * (y - 1) / 2 > t) --y;
  while ((y + 1) * MT - (y + 1) * y / 2 <= t) ++y;
  by = y;
  bx = y + (t - (y * MT - y * (y - 1) / 2));
}

// Stage a full 128x256B fp8 tile (32 KB) = 8 rounds x 256 threads x 16 B.
// LDS chunk (r, p) holds global k-chunk (p&8)|((p&7)^(r&7)) of row r
// (self-inverse swizzle; frag b64 reads are full-wave 2-way = free).
__device__ __forceinline__ void stage_tile(const char* gbase, int rowBase,
                                           unsigned char* buf, int tid) {
  #pragma unroll
  for (int it = 0; it < 8; ++it) {
    const int c = it * 256 + tid;   // chunk 0..2047
    const int r = c >> 4;           // row (16 chunks of 16 B per 256-B row)
    const int p = c & 15;
    const int kc = (p & 8) | ((p & 7) ^ (r & 7));
    const char* g = gbase + (size_t)(rowBase + r) * EB + kc * 16;
    __builtin_amdgcn_global_load_lds((gptr_t)g, (sptr_t)(buf + c * 16), 16, 0, 0);
  }
}

__global__ __launch_bounds__(256, 2) void mega_kernel(
    const float* __restrict__ emb, const int* __restrict__ labels,
    unsigned char* __restrict__ Efp8, float* __restrict__ sq,
    float* __restrict__ numpart, float* __restrict__ denpart,
    Ctrl* __restrict__ ctrl, float* __restrict__ out)
{
  __shared__ alignas(16) unsigned char As[BT * EB];  // 32 KB (full K)
  __shared__ alignas(16) unsigned char Bs[BT * EB];  // 32 KB  (total = 64 KB)

  const int b = blockIdx.x;
  const int tid = threadIdx.x;
  const int lane = tid & 63;
  const int wave = tid >> 6;
  const int waveM = wave >> 1;
  const int waveN = wave & 1;
  const int quad = lane >> 4;
  const int l16 = lane & 15;

  // ---------------- phase 0: prep 16 rows + zero partial slices -------------
  #pragma unroll
  for (int i = 0; i < 4; ++i) {
    const int row = b * 16 + i * 4 + wave;
    const float4 x = *(const float4*)(emb + (size_t)row * E + lane * 4);
    int pk = __builtin_amdgcn_cvt_pk_fp8_f32(x.x, x.y, 0, false);
    pk = __builtin_amdgcn_cvt_pk_fp8_f32(x.z, x.w, pk, true);
    ((unsigned int*)(Efp8 + (size_t)row * EB))[lane] = (unsigned int)pk;
    float s = x.x * x.x + x.y * x.y + x.z * x.z + x.w * x.w;
    #pragma unroll
    for (int off = 32; off > 0; off >>= 1) s += __shfl_down(s, off, 64);
    if (lane == 0) sq[row] = s;
  }
  {  // zero this block's slice of the partials (1024 floats each array)
    const size_t base = (size_t)b * 1024 + tid * 4;
    *(float4*)(numpart + base) = (float4){0.f, 0.f, 0.f, 0.f};
    *(float4*)(denpart + base) = (float4){0.f, 0.f, 0.f, 0.f};
  }

  // grid sync #1 (all 512 blocks co-resident: 2/CU by 64 KB LDS)
  __syncthreads();
  if (tid == 0) {
    __hip_atomic_fetch_add(&ctrl->c0, 1, __ATOMIC_ACQ_REL, __HIP_MEMORY_SCOPE_SYSTEM);
    while (__hip_atomic_load(&ctrl->c0, __ATOMIC_ACQUIRE, __HIP_MEMORY_SCOPE_SYSTEM) < NBLK)
      __builtin_amdgcn_s_sleep(1);
  }
  __syncthreads();

  // ---------------- phase 1: tiles (software-pipelined) ---------------------
  int tl[5];
  int ntl = 0;
  #pragma unroll
  for (int i = 0; i < 4; ++i) tl[ntl++] = b + NBLK * i;            // < 2048
  if (b >= NBLK - 32) tl[ntl++] = 2048 + (b - (NBLK - 32));        // 2048..2079

  const char* gbase = (const char*)Efp8;
  int cby, cbx;
  decode_tile(tl[0], cby, cbx);
  bool cdiag = (cby == cbx);
  stage_tile(gbase, cby * BT, As, tid);
  if (!cdiag) stage_tile(gbase, cbx * BT, Bs, tid);

  for (int j = 0; j < ntl; ++j) {
    __syncthreads();  // drains vmcnt(0) before barrier => tile staged

    const int rowBase = cby * BT;
    const int colBase = cbx * BT;
    const bool diag = cdiag;
    const int tby = rowBase / BT;   // tile coords of the CURRENT tile
    const int tbx = colBase / BT;
    const unsigned char* Bsrc = diag ? As : Bs;

    floatx4 acc[4][4];
    #pragma unroll
    for (int i = 0; i < 4; ++i)
      #pragma unroll
      for (int jj = 0; jj < 4; ++jj)
        acc[i][jj] = (floatx4){0.f, 0.f, 0.f, 0.f};

    #pragma unroll
    for (int ks = 0; ks < 8; ++ks) {  // K = 256 = 8 x 32
      const int kc = 2 * ks + (quad >> 1);
      const int hf = (quad & 1) * 8;
      long af[4], bf[4];
      #pragma unroll
      for (int mi = 0; mi < 4; ++mi) {
        const int r = waveM * 64 + mi * 16 + l16;
        const int p = (kc & 8) | ((kc & 7) ^ (r & 7));
        af[mi] = *(const long*)((const char*)As + r * 256 + p * 16 + hf);
      }
      #pragma unroll
      for (int ni = 0; ni < 4; ++ni) {
        const int r = waveN * 64 + ni * 16 + l16;
        const int p = (kc & 8) | ((kc & 7) ^ (r & 7));
        bf[ni] = *(const long*)((const char*)Bsrc + r * 256 + p * 16 + hf);
      }
      #pragma unroll
      for (int mi = 0; mi < 4; ++mi)
        #pragma unroll
        for (int ni = 0; ni < 4; ++ni)
          acc[mi][ni] = __builtin_amdgcn_mfma_f32_16x16x32_fp8_fp8(
              af[mi], bf[ni], acc[mi][ni], 0, 0, 0);
    }

    __syncthreads();  // all waves done reading As/Bs

    // issue next tile's staging NOW; the epilogue below hides its latency
    // (epilogue reads only registers/global, never As/Bs)
    if (j + 1 < ntl) {
      int nby, nbx;
      decode_tile(tl[j + 1], nby, nbx);
      const bool nd = (nby == nbx);
      stage_tile(gbase, nby * BT, As, tid);
      if (!nd) stage_tile(gbase, nbx * BT, Bs, tid);
      cby = nby; cbx = nbx; cdiag = nd;
    }

    // ---- epilogue (registers + global 2-way atomics; unique-writer per tile)
    float sqc[4];
    int lc[4], cg[4];
    #pragma unroll
    for (int ni = 0; ni < 4; ++ni) {
      const int col = colBase + waveN * 64 + ni * 16 + l16;
      sqc[ni] = sq[col];
      lc[ni] = labels[col];
      cg[ni] = col;
    }

    float ncp[4] = {0.f, 0.f, 0.f, 0.f};
    float dcp[4] = {0.f, 0.f, 0.f, 0.f};

    #pragma unroll
    for (int mi = 0; mi < 4; ++mi) {
      const int rbase = rowBase + waveM * 64 + mi * 16 + quad * 4;
      const float4 sqr4 = *(const float4*)(sq + rbase);
      const int4 lr4 = *(const int4*)(labels + rbase);
      const float sqr[4] = {sqr4.x, sqr4.y, sqr4.z, sqr4.w};
      const int lr[4] = {lr4.x, lr4.y, lr4.z, lr4.w};
      float npv[4], dpv[4];
      #pragma unroll
      for (int r = 0; r < 4; ++r) {
        float np = 0.f, dp = 0.f;
        #pragma unroll
        for (int ni = 0; ni < 4; ++ni) {
          float d2 = fmaxf(fmaf(-2.f, acc[mi][ni][r], sqr[r] + sqc[ni]), EPS);
          if (diag && (rbase + r == cg[ni])) d2 = EPS;  // exact diagonal
          float d = __builtin_amdgcn_sqrtf(d2);
          float rc = __builtin_amdgcn_rcpf(d + MARGIN);
          const bool same = (lr[r] == lc[ni]);
          const float dsel = same ? d : 0.f;
          const float rsel = same ? 0.f : rc;
          np += dsel; dp += rsel;
          ncp[ni] += dsel; dcp[ni] += rsel;
        }
        npv[r] = dpp_sum16(np);
        dpv[r] = dpp_sum16(dp);
      }
      const float seln = (l16 & 2) ? ((l16 & 1) ? npv[3] : npv[2])
                                   : ((l16 & 1) ? npv[1] : npv[0]);
      const float seld = (l16 & 2) ? ((l16 & 1) ? dpv[3] : dpv[2])
                                   : ((l16 & 1) ? dpv[1] : dpv[0]);
      if ((l16 >> 2) == quad) {  // one lane per row; 2-way across waveN
        const int row = rowBase + waveM * 64 + mi * 16 + l16;
        __hip_atomic_fetch_add(&numpart[(size_t)tbx * N + row], seln,
                               __ATOMIC_RELAXED, __HIP_MEMORY_SCOPE_AGENT);
        __hip_atomic_fetch_add(&denpart[(size_t)tbx * N + row], seld,
                               __ATOMIC_RELAXED, __HIP_MEMORY_SCOPE_AGENT);
      }
    }

    if (!diag) {  // col partials: reduce across quads in-wave, 2-way waveM atomics
      #pragma unroll
      for (int ni = 0; ni < 4; ++ni) {
        float n2 = ncp[ni], d2 = dcp[ni];
        n2 += __shfl_xor(n2, 16, 64); d2 += __shfl_xor(d2, 16, 64);
        n2 += __shfl_xor(n2, 32, 64); d2 += __shfl_xor(d2, 32, 64);
        if (quad == 0) {
          const int col = colBase + waveN * 64 + ni * 16 + l16;
          __hip_atomic_fetch_add(&numpart[(size_t)tby * N + col], n2,
                                 __ATOMIC_RELAXED, __HIP_MEMORY_SCOPE_AGENT);
          __hip_atomic_fetch_add(&denpart[(size_t)tby * N + col], d2,
                                 __ATOMIC_RELAXED, __HIP_MEMORY_SCOPE_AGENT);
        }
      }
    }
  }

  // ---------------- phase 2: fin (blocks 0..31) -----------------------------
  __syncthreads();
  if (tid == 0)
    __hip_atomic_fetch_add(&ctrl->c1, 1, __ATOMIC_ACQ_REL, __HIP_MEMORY_SCOPE_SYSTEM);
  if (b >= FINB) return;

  if (tid == 0) {
    while (__hip_atomic_load(&ctrl->c1, __ATOMIC_ACQUIRE, __HIP_MEMORY_SCOPE_SYSTEM) < NBLK)
      __builtin_amdgcn_s_sleep(1);
  }
  __syncthreads();

  double* shd = (double*)As;        // LDS reuse (tiles done)
  int* lastflag = (int*)(As + 64);
  int* hist = (int*)(As + 256);

  const int a = b * 256 + tid;
  float np = 0.f, dp = 0.f;
  #pragma unroll 4
  for (int k = 0; k < MT; ++k) {
    np += numpart[(size_t)k * N + a];
    dp += denpart[(size_t)k * N + a];
  }
  double s = (double)np * (double)dp;
  #pragma unroll
  for (int off = 32; off > 0; off >>= 1) s += __shfl_down(s, off, 64);
  if (lane == 0) shd[wave] = s;
  __syncthreads();
  if (tid == 0) {
    unsafeAtomicAdd(&ctrl->Ssum, shd[0] + shd[1] + shd[2] + shd[3]);
    __threadfence();  // Ssum visible before ticket
    const int prev = __hip_atomic_fetch_add(&ctrl->c2, 1, __ATOMIC_ACQ_REL,
                                            __HIP_MEMORY_SCOPE_SYSTEM);
    *lastflag = (prev == FINB - 1) ? 1 : 0;
  }
  __syncthreads();

  if (*lastflag) {
    if (tid < NUM_CLASSES) hist[tid] = 0;
    __syncthreads();
    for (int i = tid; i < N; i += 256) atomicAdd(&hist[labels[i]], 1);
    __syncthreads();
    double m = 0.0;
    if (tid < NUM_CLASSES) {
      const double cc = (double)hist[tid];
      m = cc * cc * (double)(N - cc);
    }
    #pragma unroll
    for (int off = 32; off > 0; off >>= 1) m += __shfl_down(m, off, 64);
    __syncthreads();
    if (lane == 0) shd[wave] = m;
    __syncthreads();
    if (tid == 0) {
      const double M = shd[0] + shd[1] + shd[2] + shd[3];
      const double S = __hip_atomic_load(&ctrl->Ssum, __ATOMIC_ACQUIRE,
                                         __HIP_MEMORY_SCOPE_SYSTEM);
      out[0] = (float)(S / M);
    }
  }
}

extern "C" void kernel_launch(void* const* d_in, const int* in_sizes, int n_in,
                              void* d_out, int out_size, void* d_ws, size_t ws_size,
                              hipStream_t stream) {
  const float* emb = (const float*)d_in[0];
  const int* labels = (const int*)d_in[1];
  float* out = (float*)d_out;

  // ws: Efp8[2MB] | sq[32KB] | numpart[2MB] | denpart[2MB] | Ctrl
  char* w = (char*)d_ws;
  unsigned char* Efp8 = (unsigned char*)w;
  float* sq = (float*)(w + (size_t)N * EB);
  float* numpart = sq + N;
  float* denpart = numpart + (size_t)MT * N;
  Ctrl* ctrl = (Ctrl*)(denpart + (size_t)MT * N);

  (void)hipMemsetAsync(ctrl, 0, sizeof(Ctrl), stream);
  mega_kernel<<<NBLK, 256, 0, stream>>>(emb, labels, Efp8, sq, numpart, denpart,
                                        ctrl, out);
}